// Round 4
// baseline (541.938 us; speedup 1.0000x reference)
//
#include <hip/hip_runtime.h>
#include <cstdint>
#include <cstddef>

typedef unsigned short u16;
typedef __bf16 bf16x8 __attribute__((ext_vector_type(8)));
typedef float f32x4 __attribute__((ext_vector_type(4)));

#define SLEN 2048
#define NHEADS 16
#define NGRP 4

__device__ inline float bf2f(u16 u) { return __uint_as_float(((unsigned)u) << 16); }
__device__ inline u16 f2bf(float f) {
    unsigned u = __float_as_uint(f);
    u += 0x7fffu + ((u >> 16) & 1u);
    return (u16)(u >> 16);
}

__device__ inline f32x4 mfma16(bf16x8 a, bf16x8 b, f32x4 c) {
    return __builtin_amdgcn_mfma_f32_16x16x32_bf16(a, b, c, 0, 0, 0);
}

__device__ inline void memfence_compiler() { __asm__ volatile("" ::: "memory"); }

// async global->LDS, 16B per lane; LDS dest = wave-uniform base + lane*16
__device__ inline void cp16(const u16* g, u16* l) {
    __builtin_amdgcn_global_load_lds(
        (__attribute__((address_space(1))) void*)(u16*)g,
        (__attribute__((address_space(3))) void*)l, 16, 0, 0);
}

// ---------------- fp32 -> bf16 convert, 4 elems/thread ----------------
__global__ __launch_bounds__(256) void convert_k(const float* __restrict__ in, u16* __restrict__ out,
                                                 long n) {
    long i = ((long)blockIdx.x * 256 + threadIdx.x) * 4;
    if (i >= n) return;
    float4 v = *(const float4*)(in + i);
    ushort4 o;
    o.x = f2bf(v.x); o.y = f2bf(v.y); o.z = f2bf(v.z); o.w = f2bf(v.w);
    *(ushort4*)(out + i) = o;
}

__global__ __launch_bounds__(128) void convert_small_k(const float* __restrict__ qw,
                                                       const float* __restrict__ kw,
                                                       u16* qwb, u16* kwb) {
    int t = threadIdx.x;
    qwb[t] = f2bf(qw[t]);
    kwb[t] = f2bf(kw[t]);
}

// ---------------- fp32 transpose + convert: in (R,C) fp32 -> out (C,R) bf16 ----------------
__global__ __launch_bounds__(256) void transpose_f32_k(const float* __restrict__ in,
                                                       u16* __restrict__ out, int R, int C) {
    __shared__ u16 tile[64][65];
    const int tid = threadIdx.x;
    const long r0 = (long)blockIdx.y * 64, c0 = (long)blockIdx.x * 64;
    for (int j = 0; j < 4; j++) {
        int c = j * 256 + tid;
        int lr = c >> 4, lc = (c & 15) * 4;
        float4 v = *(const float4*)&in[(r0 + lr) * (long)C + c0 + lc];
        tile[lr][lc + 0] = f2bf(v.x); tile[lr][lc + 1] = f2bf(v.y);
        tile[lr][lc + 2] = f2bf(v.z); tile[lr][lc + 3] = f2bf(v.w);
    }
    __syncthreads();
    for (int j = 0; j < 4; j++) {
        int c = j * 256 + tid;
        int orow = c >> 4, oc = (c & 15) * 4;
        ushort4 vv;
        vv.x = tile[oc + 0][orow]; vv.y = tile[oc + 1][orow];
        vv.z = tile[oc + 2][orow]; vv.w = tile[oc + 3][orow];
        *(ushort4*)&out[(c0 + orow) * (long)R + r0 + oc] = vv;
    }
}

// ---------------- bf16 transpose: in (R,C) -> out (C,R) ----------------
__global__ __launch_bounds__(256) void transpose_bf_k(const u16* __restrict__ in,
                                                      u16* __restrict__ out, int R, int C) {
    __shared__ u16 tile[64][65];
    const int tid = threadIdx.x;
    const long r0 = (long)blockIdx.y * 64, c0 = (long)blockIdx.x * 64;
    for (int j = 0; j < 4; j++) {
        int c = j * 256 + tid;
        int lr = c >> 4, lc = (c & 15) * 4;
        ushort4 vv = *(const ushort4*)&in[(r0 + lr) * (long)C + c0 + lc];
        tile[lr][lc + 0] = vv.x; tile[lr][lc + 1] = vv.y;
        tile[lr][lc + 2] = vv.z; tile[lr][lc + 3] = vv.w;
    }
    __syncthreads();
    for (int j = 0; j < 4; j++) {
        int c = j * 256 + tid;
        int orow = c >> 4, oc = (c & 15) * 4;
        ushort4 vv;
        vv.x = tile[oc + 0][orow]; vv.y = tile[oc + 1][orow];
        vv.z = tile[oc + 2][orow]; vv.w = tile[oc + 3][orow];
        *(ushort4*)&out[(c0 + orow) * (long)R + r0 + oc] = vv;
    }
}

// ---------------- GEMM: C(M,N) = A(M,K) * Bt(N,K)^T, bf16 in, OutT out ----------------
template <typename OutT>
__global__ __launch_bounds__(256) void gemm_bt(const u16* __restrict__ A, const u16* __restrict__ Bt,
                                               OutT* __restrict__ C, int M, int N, int K) {
    __shared__ u16 As[128 * 32];
    __shared__ u16 Bs[128 * 32];
    const int tid = threadIdx.x;
    const int lane = tid & 63, wave = tid >> 6;
    const int l15 = lane & 15, quad = lane >> 4;
    const long m0 = (long)blockIdx.y * 128, n0 = (long)blockIdx.x * 128;
    const int wm = (wave >> 1) * 64, wn = (wave & 1) * 64;

    f32x4 acc[4][4];
    for (int i = 0; i < 4; i++)
        for (int j = 0; j < 4; j++) acc[i][j] = {0.f, 0.f, 0.f, 0.f};

    const u16* aG = A + (m0 + wave * 32 + (lane >> 2)) * (long)K + (lane & 3) * 8;
    const u16* bG = Bt + (n0 + wave * 32 + (lane >> 2)) * (long)K + (lane & 3) * 8;
    u16* aL = &As[wave * 1024];
    u16* bL = &Bs[wave * 1024];
    const long rowK16 = 16L * K;

    for (int kt = 0; kt < K; kt += 32) {
        cp16(aG + kt, aL);
        cp16(aG + kt + rowK16, aL + 512);
        cp16(bG + kt, bL);
        cp16(bG + kt + rowK16, bL + 512);
        __syncthreads();
        bf16x8 af[4], bfr[4];
        for (int mi = 0; mi < 4; mi++)
            af[mi] = *(const bf16x8*)&As[(wm + mi * 16 + l15) * 32 + quad * 8];
        for (int ni = 0; ni < 4; ni++)
            bfr[ni] = *(const bf16x8*)&Bs[(wn + ni * 16 + l15) * 32 + quad * 8];
        for (int mi = 0; mi < 4; mi++)
            for (int ni = 0; ni < 4; ni++)
                acc[mi][ni] = mfma16(af[mi], bfr[ni], acc[mi][ni]);
        __syncthreads();
    }
    for (int mi = 0; mi < 4; mi++)
        for (int r = 0; r < 4; r++) {
            long row = m0 + wm + mi * 16 + quad * 4 + r;
            OutT* crow = C + row * (long)N + n0 + wn + l15;
            for (int ni = 0; ni < 4; ni++) {
                float v = acc[mi][ni][r];
                if constexpr (sizeof(OutT) == 2) crow[ni * 16] = f2bf(v);
                else crow[ni * 16] = v;
            }
        }
}

// ---------------- RMSNorm + RoPE + scale, one wave per 128-elem row ----------------
__global__ __launch_bounds__(256) void normrope(u16* __restrict__ buf, const u16* __restrict__ w,
                                                const u16* __restrict__ cosb, const u16* __restrict__ sinb,
                                                int heads, float scale) {
    const int row = blockIdx.x * 4 + (threadIdx.x >> 6);
    const int lane = threadIdx.x & 63;
    u16* p = buf + (long)row * 128;
    float x1 = bf2f(p[lane]);
    float x2 = bf2f(p[lane + 64]);
    float ss = x1 * x1 + x2 * x2;
    for (int off = 1; off < 64; off <<= 1) ss += __shfl_xor(ss, off);
    float inv = rsqrtf(ss * (1.f / 128.f) + 1e-6f);
    int s = (row / heads) % SLEN;
    float c1 = bf2f(cosb[s * 128 + lane]), c2 = bf2f(cosb[s * 128 + 64 + lane]);
    float s1 = bf2f(sinb[s * 128 + lane]), s2 = bf2f(sinb[s * 128 + 64 + lane]);
    float w1 = bf2f(w[lane]), w2 = bf2f(w[lane + 64]);
    float y1 = x1 * inv * w1, y2 = x2 * inv * w2;
    p[lane]      = f2bf((y1 * c1 - y2 * s1) * scale);
    p[lane + 64] = f2bf((y2 * c2 + y1 * s2) * scale);
}

// ---------------- causal flash attention ----------------
__global__ __launch_bounds__(256) void attn(const u16* __restrict__ q, const u16* __restrict__ k,
                                            const u16* __restrict__ vT, u16* __restrict__ ctx) {
    __shared__ u16 Ks[64][136];   // [t][d]
    __shared__ u16 Vt[128][72];   // [d][t]
    __shared__ u16 Ps[4][16][72]; // per-wave P [row][t]
    const int tid = threadIdx.x;
    const int lane = tid & 63, wave = tid >> 6;
    const int l15 = lane & 15, quad = lane >> 4;
    const int qt = blockIdx.x, h = blockIdx.y, b = blockIdx.z;
    const int g = h >> 2;
    const int q0 = qt * 64;
    const int qrow = q0 + wave * 16 + l15;

    bf16x8 qa[4];
    {
        const u16* qp = q + ((long)(b * SLEN + qrow) * NHEADS + h) * 128 + quad * 8;
        for (int kc = 0; kc < 4; kc++) qa[kc] = *(const bf16x8*)(qp + kc * 32);
    }
    float m_i[4], l_i[4];
    f32x4 o[8];
    for (int r = 0; r < 4; r++) { m_i[r] = -__builtin_inff(); l_i[r] = 0.f; }
    for (int nf = 0; nf < 8; nf++) o[nf] = {0.f, 0.f, 0.f, 0.f};

    for (int t0 = 0; t0 <= q0; t0 += 64) {
        __syncthreads();
        for (int j = 0; j < 4; j++) {
            int c = j * 256 + tid;
            int tr = c >> 4, d8 = (c & 15) * 8;
            *(bf16x8*)&Ks[tr][d8] =
                *(const bf16x8*)(k + ((long)(b * SLEN + t0 + tr) * NGRP + g) * 128 + d8);
            int dv = c >> 3, t8 = (c & 7) * 8;
            *(bf16x8*)&Vt[dv][t8] =
                *(const bf16x8*)(vT + (long)(g * 128 + dv) * 4096 + b * SLEN + t0 + t8);
        }
        __syncthreads();
        f32x4 sc[4];
        for (int nf = 0; nf < 4; nf++) sc[nf] = {0.f, 0.f, 0.f, 0.f};
        for (int kc = 0; kc < 4; kc++)
            for (int nf = 0; nf < 4; nf++) {
                bf16x8 kb = *(const bf16x8*)&Ks[nf * 16 + l15][kc * 32 + quad * 8];
                sc[nf] = mfma16(qa[kc], kb, sc[nf]);
            }
        if (t0 == q0) {
            for (int nf = 0; nf < 4; nf++)
                for (int r = 0; r < 4; r++) {
                    int tg = t0 + nf * 16 + l15;
                    int sg = q0 + wave * 16 + quad * 4 + r;
                    if (tg > sg) sc[nf][r] = -__builtin_inff();
                }
        }
        for (int r = 0; r < 4; r++) {
            float mx = fmaxf(fmaxf(sc[0][r], sc[1][r]), fmaxf(sc[2][r], sc[3][r]));
            for (int off = 1; off < 16; off <<= 1) mx = fmaxf(mx, __shfl_xor(mx, off));
            float mn = fmaxf(m_i[r], mx);
            float alpha = __expf(m_i[r] - mn);
            m_i[r] = mn;
            float rs = 0.f;
            for (int nf = 0; nf < 4; nf++) {
                float p = __expf(sc[nf][r] - mn);
                sc[nf][r] = p;
                rs += p;
            }
            for (int off = 1; off < 16; off <<= 1) rs += __shfl_xor(rs, off);
            l_i[r] = l_i[r] * alpha + rs;
            for (int nf = 0; nf < 8; nf++) o[nf][r] = o[nf][r] * alpha;
            for (int nf = 0; nf < 4; nf++)
                Ps[wave][quad * 4 + r][nf * 16 + l15] = f2bf(sc[nf][r]);
        }
        memfence_compiler();
        for (int kc = 0; kc < 2; kc++) {
            bf16x8 pa = *(const bf16x8*)&Ps[wave][l15][kc * 32 + quad * 8];
            for (int nf = 0; nf < 8; nf++) {
                bf16x8 vb = *(const bf16x8*)&Vt[nf * 16 + l15][kc * 32 + quad * 8];
                o[nf] = mfma16(pa, vb, o[nf]);
            }
        }
        memfence_compiler();
    }
    for (int r = 0; r < 4; r++) {
        float inv = 1.f / l_i[r];
        int srow = q0 + wave * 16 + quad * 4 + r;
        u16* cp = ctx + ((long)(b * SLEN + srow) * NHEADS + h) * 128 + l15;
        for (int nf = 0; nf < 8; nf++) cp[nf * 16] = f2bf(o[nf][r] * inv);
    }
}

extern "C" void kernel_launch(void* const* d_in, const int* in_sizes, int n_in,
                              void* d_out, int out_size, void* d_ws, size_t ws_size,
                              hipStream_t stream) {
    const float* x    = (const float*)d_in[0];
    // d_in[1] = mask (unused; causality from indices)
    const float* cosi = (const float*)d_in[2];
    const float* sini = (const float*)d_in[3];
    const float* Wq   = (const float*)d_in[4];
    const float* Wk   = (const float*)d_in[5];
    const float* Wv   = (const float*)d_in[6];
    const float* Wo   = (const float*)d_in[7];
    const float* qw   = (const float*)d_in[8];
    const float* kw   = (const float*)d_in[9];
    float* out = (float*)d_out;
    char* ws = (char*)d_ws;

    const size_t MB = 1 << 20;
    u16* qb   = (u16*)(ws);              // 4096x2048 bf16 = 16 MB   [0,16M)
    u16* kb   = (u16*)(ws + 16 * MB);    // 4096x512        = 4 MB   [16,20M)
    u16* vb   = (u16*)(ws + 20 * MB);    // 4096x512        = 4 MB   [20,24M)
    u16* vTb  = (u16*)(ws + 24 * MB);    // 512x4096        = 4 MB   [24,28M)
    u16* xbf  = (u16*)(ws + 28 * MB);    // 4096x2048       = 16 MB  [28,44M)  dead after QKV
    u16* ctx  = (u16*)(ws + 28 * MB);    // reuses xbf region
    u16* wT1  = (u16*)(ws + 44 * MB);    // wqT then woT: 2048x2048 = 8 MB [44,52M)
    u16* wkT  = (u16*)(ws + 52 * MB);    // 512x2048        = 2 MB   [52,54M)
    u16* wvT  = (u16*)(ws + 54 * MB);    // 512x2048        = 2 MB   [54,56M)
    u16* cosb = (u16*)(ws + 56 * MB);            // 2048x128 = 512 KB
    u16* sinb = (u16*)(ws + 56 * MB + 524288);   // 512 KB
    u16* qwb  = (u16*)(ws + 57 * MB);
    u16* kwb  = (u16*)(ws + 57 * MB + 256);

    convert_k<<<8192, 256, 0, stream>>>(x, xbf, 8388608L);
    convert_k<<<256, 256, 0, stream>>>(cosi, cosb, 262144L);
    convert_k<<<256, 256, 0, stream>>>(sini, sinb, 262144L);
    convert_small_k<<<1, 128, 0, stream>>>(qw, kw, qwb, kwb);

    transpose_f32_k<<<dim3(32, 32), 256, 0, stream>>>(Wq, wT1, 2048, 2048);
    transpose_f32_k<<<dim3(8, 32), 256, 0, stream>>>(Wk, wkT, 2048, 512);
    transpose_f32_k<<<dim3(8, 32), 256, 0, stream>>>(Wv, wvT, 2048, 512);

    gemm_bt<u16><<<dim3(16, 32), 256, 0, stream>>>(xbf, wT1, qb, 4096, 2048, 2048);
    gemm_bt<u16><<<dim3(4, 32), 256, 0, stream>>>(xbf, wkT, kb, 4096, 512, 2048);
    gemm_bt<u16><<<dim3(4, 32), 256, 0, stream>>>(xbf, wvT, vb, 4096, 512, 2048);

    transpose_bf_k<<<dim3(8, 64), 256, 0, stream>>>(vb, vTb, 4096, 512);

    normrope<<<16384, 256, 0, stream>>>(qb, qwb, cosb, sinb, NHEADS, 0.08838834764831845f);
    normrope<<<4096, 256, 0, stream>>>(kb, kwb, cosb, sinb, NGRP, 1.0f);

    attn<<<dim3(32, 16, 2), 256, 0, stream>>>(qb, kb, vTb, ctx);

    transpose_f32_k<<<dim3(32, 32), 256, 0, stream>>>(Wo, wT1, 2048, 2048);

    gemm_bt<float><<<dim3(16, 32), 256, 0, stream>>>(ctx, wT1, out, 4096, 2048, 2048);
}

// Round 5
// 500.067 us; speedup vs baseline: 1.0837x; 1.0837x over previous
//
#include <hip/hip_runtime.h>
#include <cstdint>
#include <cstddef>

typedef unsigned short u16;
typedef __bf16 bf16x8 __attribute__((ext_vector_type(8)));
typedef float f32x4 __attribute__((ext_vector_type(4)));

#define SLEN 2048
#define NHEADS 16
#define NGRP 4

__device__ inline float bf2f(u16 u) { return __uint_as_float(((unsigned)u) << 16); }
__device__ inline u16 f2bf(float f) {
    unsigned u = __float_as_uint(f);
    u += 0x7fffu + ((u >> 16) & 1u);
    return (u16)(u >> 16);
}

__device__ inline f32x4 mfma16(bf16x8 a, bf16x8 b, f32x4 c) {
    return __builtin_amdgcn_mfma_f32_16x16x32_bf16(a, b, c, 0, 0, 0);
}

__device__ inline void memfence_compiler() { __asm__ volatile("" ::: "memory"); }

// async global->LDS, 16B per lane; LDS dest = wave-uniform base + lane*16
__device__ inline void cp16(const u16* g, u16* l) {
    __builtin_amdgcn_global_load_lds(
        (__attribute__((address_space(1))) void*)(u16*)g,
        (__attribute__((address_space(3))) void*)l, 16, 0, 0);
}

// ---------------- fp32 -> bf16 convert, 4 elems/thread ----------------
__global__ __launch_bounds__(256) void convert_k(const float* __restrict__ in, u16* __restrict__ out,
                                                 long n) {
    long i = ((long)blockIdx.x * 256 + threadIdx.x) * 4;
    if (i >= n) return;
    float4 v = *(const float4*)(in + i);
    ushort4 o;
    o.x = f2bf(v.x); o.y = f2bf(v.y); o.z = f2bf(v.z); o.w = f2bf(v.w);
    *(ushort4*)(out + i) = o;
}

__global__ __launch_bounds__(128) void convert_small_k(const float* __restrict__ qw,
                                                       const float* __restrict__ kw,
                                                       u16* qwb, u16* kwb) {
    int t = threadIdx.x;
    qwb[t] = f2bf(qw[t]);
    kwb[t] = f2bf(kw[t]);
}

// ---------------- fp32 transpose + convert: in (R,C) fp32 -> out (C,R) bf16 ----------------
__global__ __launch_bounds__(256) void transpose_f32_k(const float* __restrict__ in,
                                                       u16* __restrict__ out, int R, int C) {
    __shared__ u16 tile[64][65];
    const int tid = threadIdx.x;
    const long r0 = (long)blockIdx.y * 64, c0 = (long)blockIdx.x * 64;
    for (int j = 0; j < 4; j++) {
        int c = j * 256 + tid;
        int lr = c >> 4, lc = (c & 15) * 4;
        float4 v = *(const float4*)&in[(r0 + lr) * (long)C + c0 + lc];
        tile[lr][lc + 0] = f2bf(v.x); tile[lr][lc + 1] = f2bf(v.y);
        tile[lr][lc + 2] = f2bf(v.z); tile[lr][lc + 3] = f2bf(v.w);
    }
    __syncthreads();
    for (int j = 0; j < 4; j++) {
        int c = j * 256 + tid;
        int orow = c >> 4, oc = (c & 15) * 4;
        ushort4 vv;
        vv.x = tile[oc + 0][orow]; vv.y = tile[oc + 1][orow];
        vv.z = tile[oc + 2][orow]; vv.w = tile[oc + 3][orow];
        *(ushort4*)&out[(c0 + orow) * (long)R + r0 + oc] = vv;
    }
}

// ---------------- bf16 transpose w/ input row stride: in (R,C)@inRS -> out (C,R) ----------------
__global__ __launch_bounds__(256) void transpose_bf_k(const u16* __restrict__ in, long inRS,
                                                      u16* __restrict__ out, int R, int C) {
    __shared__ u16 tile[64][65];
    const int tid = threadIdx.x;
    const long r0 = (long)blockIdx.y * 64, c0 = (long)blockIdx.x * 64;
    for (int j = 0; j < 4; j++) {
        int c = j * 256 + tid;
        int lr = c >> 4, lc = (c & 15) * 4;
        ushort4 vv = *(const ushort4*)&in[(r0 + lr) * inRS + c0 + lc];
        tile[lr][lc + 0] = vv.x; tile[lr][lc + 1] = vv.y;
        tile[lr][lc + 2] = vv.z; tile[lr][lc + 3] = vv.w;
    }
    __syncthreads();
    for (int j = 0; j < 4; j++) {
        int c = j * 256 + tid;
        int orow = c >> 4, oc = (c & 15) * 4;
        ushort4 vv;
        vv.x = tile[oc + 0][orow]; vv.y = tile[oc + 1][orow];
        vv.z = tile[oc + 2][orow]; vv.w = tile[oc + 3][orow];
        *(ushort4*)&out[(c0 + orow) * (long)R + r0 + oc] = vv;
    }
}

// ---------------- GEMM: C(M,N) = A(M,K) * Bt(N,K)^T, bf16 in, OutT out ----------------
template <typename OutT>
__global__ __launch_bounds__(256) void gemm_bt(const u16* __restrict__ A, const u16* __restrict__ Bt,
                                               OutT* __restrict__ C, int M, int N, int K) {
    __shared__ u16 As[128 * 32];
    __shared__ u16 Bs[128 * 32];
    const int tid = threadIdx.x;
    const int lane = tid & 63, wave = tid >> 6;
    const int l15 = lane & 15, quad = lane >> 4;
    const long m0 = (long)blockIdx.y * 128, n0 = (long)blockIdx.x * 128;
    const int wm = (wave >> 1) * 64, wn = (wave & 1) * 64;

    f32x4 acc[4][4];
    for (int i = 0; i < 4; i++)
        for (int j = 0; j < 4; j++) acc[i][j] = {0.f, 0.f, 0.f, 0.f};

    const u16* aG = A + (m0 + wave * 32 + (lane >> 2)) * (long)K + (lane & 3) * 8;
    const u16* bG = Bt + (n0 + wave * 32 + (lane >> 2)) * (long)K + (lane & 3) * 8;
    u16* aL = &As[wave * 1024];
    u16* bL = &Bs[wave * 1024];
    const long rowK16 = 16L * K;

    for (int kt = 0; kt < K; kt += 32) {
        cp16(aG + kt, aL);
        cp16(aG + kt + rowK16, aL + 512);
        cp16(bG + kt, bL);
        cp16(bG + kt + rowK16, bL + 512);
        __syncthreads();
        bf16x8 af[4], bfr[4];
        for (int mi = 0; mi < 4; mi++)
            af[mi] = *(const bf16x8*)&As[(wm + mi * 16 + l15) * 32 + quad * 8];
        for (int ni = 0; ni < 4; ni++)
            bfr[ni] = *(const bf16x8*)&Bs[(wn + ni * 16 + l15) * 32 + quad * 8];
        for (int mi = 0; mi < 4; mi++)
            for (int ni = 0; ni < 4; ni++)
                acc[mi][ni] = mfma16(af[mi], bfr[ni], acc[mi][ni]);
        __syncthreads();
    }
    for (int mi = 0; mi < 4; mi++)
        for (int r = 0; r < 4; r++) {
            long row = m0 + wm + mi * 16 + quad * 4 + r;
            OutT* crow = C + row * (long)N + n0 + wn + l15;
            for (int ni = 0; ni < 4; ni++) {
                float v = acc[mi][ni][r];
                if constexpr (sizeof(OutT) == 2) crow[ni * 16] = f2bf(v);
                else crow[ni * 16] = v;
            }
        }
}

// ---------------- RMSNorm + RoPE + scale (fp32 cos/sin), one wave per 128-elem row ----------------
__global__ __launch_bounds__(256) void normrope(u16* __restrict__ buf, long rowstride, int heads,
                                                const u16* __restrict__ w,
                                                const float* __restrict__ cosf, const float* __restrict__ sinf,
                                                float scale) {
    const int row = blockIdx.x * 4 + (threadIdx.x >> 6);
    const int lane = threadIdx.x & 63;
    u16* p = buf + (long)(row / heads) * rowstride + (row % heads) * 128;
    float x1 = bf2f(p[lane]);
    float x2 = bf2f(p[lane + 64]);
    float ss = x1 * x1 + x2 * x2;
    for (int off = 1; off < 64; off <<= 1) ss += __shfl_xor(ss, off);
    float inv = rsqrtf(ss * (1.f / 128.f) + 1e-6f);
    int s = (row / heads) % SLEN;
    float c1 = cosf[s * 128 + lane], c2 = cosf[s * 128 + 64 + lane];
    float s1 = sinf[s * 128 + lane], s2 = sinf[s * 128 + 64 + lane];
    float w1 = bf2f(w[lane]), w2 = bf2f(w[lane + 64]);
    float y1 = x1 * inv * w1, y2 = x2 * inv * w2;
    p[lane]      = f2bf((y1 * c1 - y2 * s1) * scale);
    p[lane + 64] = f2bf((y2 * c2 + y1 * s2) * scale);
}

// ---------------- causal flash attention v2: 128 q-rows/block, 2 m-frags/wave ----------------
// qkv: (B*S, 3072) fused [q 0:2048 | k 2048:2560 | v 2560:3072], normed+roped
// vT: (512, B*S); ctx out: (B*S, 2048)
__global__ __launch_bounds__(256) void attn(const u16* __restrict__ qkv, const u16* __restrict__ vT,
                                            u16* __restrict__ ctx) {
    __shared__ u16 Ks[64][136];   // [t][d]   row stride 272B ≡ 16 mod 128 (2-way, free)
    __shared__ u16 Vt[128][72];   // [d][t]   row stride 144B ≡ 16 mod 128
    __shared__ u16 Ps[4][32][40]; // per-wave P [row][t-half] row stride 80B (odd*16B)
    const int tid = threadIdx.x;
    const int lane = tid & 63, wave = tid >> 6;
    const int l15 = lane & 15, quad = lane >> 4;
    const int qt = 15 - blockIdx.x;   // longest blocks first
    const int h = blockIdx.y, b = blockIdx.z;
    const int g = h >> 2;
    const int q0 = qt * 128;
    const int wrow_lo = q0 + wave * 32;

    bf16x8 qa[2][4];
    for (int m = 0; m < 2; m++) {
        const u16* qp = qkv + (long)(b * SLEN + wrow_lo + m * 16 + l15) * 3072 + h * 128 + quad * 8;
        for (int kc = 0; kc < 4; kc++) qa[m][kc] = *(const bf16x8*)(qp + kc * 32);
    }
    float m_i[2][4], l_i[2][4];
    f32x4 o[2][8];
    for (int m = 0; m < 2; m++)
        for (int r = 0; r < 4; r++) { m_i[m][r] = -__builtin_inff(); l_i[m][r] = 0.f; }
    for (int m = 0; m < 2; m++)
        for (int nf = 0; nf < 8; nf++) o[m][nf] = {0.f, 0.f, 0.f, 0.f};

    for (int t0 = 0; t0 < q0 + 128; t0 += 64) {
        __syncthreads();
        #pragma unroll
        for (int j = 0; j < 4; j++) {
            int c = j * 256 + tid;
            int tr = c >> 4, d8 = (c & 15) * 8;
            *(bf16x8*)&Ks[tr][d8] =
                *(const bf16x8*)(qkv + (long)(b * SLEN + t0 + tr) * 3072 + 2048 + g * 128 + d8);
            int dv = c >> 3, t8 = (c & 7) * 8;
            *(bf16x8*)&Vt[dv][t8] =
                *(const bf16x8*)(vT + (long)(g * 128 + dv) * 4096 + b * SLEN + t0 + t8);
        }
        __syncthreads();
        if (t0 > wrow_lo + 31) continue;   // this wave's rows all precede the tile

        f32x4 sc[2][4];
        for (int m = 0; m < 2; m++)
            for (int nf = 0; nf < 4; nf++) sc[m][nf] = {0.f, 0.f, 0.f, 0.f};
        #pragma unroll
        for (int kc = 0; kc < 4; kc++)
            #pragma unroll
            for (int nf = 0; nf < 4; nf++) {
                bf16x8 kb = *(const bf16x8*)&Ks[nf * 16 + l15][kc * 32 + quad * 8];
                sc[0][nf] = mfma16(qa[0][kc], kb, sc[0][nf]);
                sc[1][nf] = mfma16(qa[1][kc], kb, sc[1][nf]);
            }
        if (t0 + 63 > wrow_lo) { // tile overlaps diagonal for this wave
            for (int m = 0; m < 2; m++)
                for (int nf = 0; nf < 4; nf++)
                    for (int r = 0; r < 4; r++) {
                        int tg = t0 + nf * 16 + l15;
                        int sg = wrow_lo + m * 16 + quad * 4 + r;
                        if (tg > sg) sc[m][nf][r] = -__builtin_inff();
                    }
        }
        // online softmax (rows owned by (quad,r); t spread over l15 within 16-lane groups)
        for (int m = 0; m < 2; m++)
            for (int r = 0; r < 4; r++) {
                float mx = fmaxf(fmaxf(sc[m][0][r], sc[m][1][r]), fmaxf(sc[m][2][r], sc[m][3][r]));
                for (int off = 1; off < 16; off <<= 1) mx = fmaxf(mx, __shfl_xor(mx, off));
                float mn = fmaxf(m_i[m][r], mx);
                float alpha = __expf(m_i[m][r] - mn);
                m_i[m][r] = mn;
                float rs = 0.f;
                for (int nf = 0; nf < 4; nf++) {
                    float p = __expf(sc[m][nf][r] - mn);
                    sc[m][nf][r] = p;
                    rs += p;
                }
                for (int off = 1; off < 16; off <<= 1) rs += __shfl_xor(rs, off);
                l_i[m][r] = l_i[m][r] * alpha + rs;
                for (int nf = 0; nf < 8; nf++) o[m][nf][r] *= alpha;
            }
        // PV in two t-halves through wave-private LDS (C-layout -> A-layout)
        #pragma unroll
        for (int half = 0; half < 2; half++) {
            for (int m = 0; m < 2; m++)
                for (int r = 0; r < 4; r++) {
                    Ps[wave][m * 16 + quad * 4 + r][l15]      = f2bf(sc[m][half * 2 + 0][r]);
                    Ps[wave][m * 16 + quad * 4 + r][16 + l15] = f2bf(sc[m][half * 2 + 1][r]);
                }
            memfence_compiler();
            bf16x8 pa0 = *(const bf16x8*)&Ps[wave][l15][quad * 8];
            bf16x8 pa1 = *(const bf16x8*)&Ps[wave][16 + l15][quad * 8];
            #pragma unroll
            for (int nf = 0; nf < 8; nf++) {
                bf16x8 vb = *(const bf16x8*)&Vt[nf * 16 + l15][half * 32 + quad * 8];
                o[0][nf] = mfma16(pa0, vb, o[0][nf]);
                o[1][nf] = mfma16(pa1, vb, o[1][nf]);
            }
            memfence_compiler();
        }
    }
    for (int m = 0; m < 2; m++)
        for (int r = 0; r < 4; r++) {
            float inv = 1.f / l_i[m][r];
            int srow = wrow_lo + m * 16 + quad * 4 + r;
            u16* cp = ctx + (long)(b * SLEN + srow) * 2048 + h * 128 + l15;
            for (int nf = 0; nf < 8; nf++) cp[nf * 16] = f2bf(o[m][nf][r] * inv);
        }
}

extern "C" void kernel_launch(void* const* d_in, const int* in_sizes, int n_in,
                              void* d_out, int out_size, void* d_ws, size_t ws_size,
                              hipStream_t stream) {
    const float* x    = (const float*)d_in[0];
    // d_in[1] = mask (unused; causality from indices)
    const float* cosi = (const float*)d_in[2];
    const float* sini = (const float*)d_in[3];
    const float* Wq   = (const float*)d_in[4];
    const float* Wk   = (const float*)d_in[5];
    const float* Wv   = (const float*)d_in[6];
    const float* Wo   = (const float*)d_in[7];
    const float* qw   = (const float*)d_in[8];
    const float* kw   = (const float*)d_in[9];
    float* out = (float*)d_out;
    char* ws = (char*)d_ws;

    const size_t MB = 1 << 20;
    u16* qkvb  = (u16*)(ws);             // 4096x3072 bf16 = 24 MB  [0,24)
    u16* vTb   = (u16*)(ws + 24 * MB);   // 512x4096        = 4 MB  [24,28)
    u16* xbf   = (u16*)(ws + 28 * MB);   // 4096x2048       = 16 MB [28,44) dead after QKV GEMM
    u16* ctx   = (u16*)(ws + 28 * MB);   // reuses xbf region
    u16* wqkvT = (u16*)(ws + 44 * MB);   // 3072x2048       = 12 MB [44,56) dead after QKV GEMM
    u16* woT   = (u16*)(ws + 44 * MB);   // reuses wqkvT region (8 MB)
    u16* qwb   = (u16*)(ws + 56 * MB);
    u16* kwb   = (u16*)(ws + 56 * MB + 256);

    convert_k<<<8192, 256, 0, stream>>>(x, xbf, 8388608L);
    convert_small_k<<<1, 128, 0, stream>>>(qw, kw, qwb, kwb);

    // fused weight: rows 0..2047 = Wq^T, 2048..2559 = Wk^T, 2560..3071 = Wv^T
    transpose_f32_k<<<dim3(32, 32), 256, 0, stream>>>(Wq, wqkvT, 2048, 2048);
    transpose_f32_k<<<dim3(8, 32), 256, 0, stream>>>(Wk, wqkvT + 2048L * 2048, 2048, 512);
    transpose_f32_k<<<dim3(8, 32), 256, 0, stream>>>(Wv, wqkvT + 2560L * 2048, 2048, 512);

    gemm_bt<u16><<<dim3(24, 32), 256, 0, stream>>>(xbf, wqkvT, qkvb, 4096, 3072, 2048);

    // v columns (2560..3071) -> vT (512, 4096)
    transpose_bf_k<<<dim3(8, 64), 256, 0, stream>>>(qkvb + 2560, 3072L, vTb, 4096, 512);

    normrope<<<16384, 256, 0, stream>>>(qkvb, 3072L, NHEADS, qwb, cosi, sini, 0.08838834764831845f);
    normrope<<<4096, 256, 0, stream>>>(qkvb + 2048, 3072L, NGRP, kwb, cosi, sini, 1.0f);

    // Wo^T into the (now dead) wqkvT region
    transpose_f32_k<<<dim3(32, 32), 256, 0, stream>>>(Wo, woT, 2048, 2048);

    attn<<<dim3(16, 16, 2), 256, 0, stream>>>(qkvb, vTb, ctx);

    gemm_bt<float><<<dim3(16, 32), 256, 0, stream>>>(ctx, woT, out, 4096, 2048, 2048);
}

// Round 6
// 462.854 us; speedup vs baseline: 1.1709x; 1.0804x over previous
//
#include <hip/hip_runtime.h>
#include <cstdint>
#include <cstddef>

typedef unsigned short u16;
typedef __bf16 bf16x8 __attribute__((ext_vector_type(8)));
typedef float f32x4 __attribute__((ext_vector_type(4)));

#define SLEN 2048
#define NHEADS 16
#define NGRP 4

__device__ inline float bf2f(u16 u) { return __uint_as_float(((unsigned)u) << 16); }
__device__ inline u16 f2bf(float f) {
    unsigned u = __float_as_uint(f);
    u += 0x7fffu + ((u >> 16) & 1u);
    return (u16)(u >> 16);
}

__device__ inline f32x4 mfma16(bf16x8 a, bf16x8 b, f32x4 c) {
    return __builtin_amdgcn_mfma_f32_16x16x32_bf16(a, b, c, 0, 0, 0);
}

__device__ inline void memfence_compiler() { __asm__ volatile("" ::: "memory"); }

// async global->LDS, 16B per lane; LDS dest = wave-uniform base + lane*16
__device__ inline void cp16(const u16* g, u16* l) {
    __builtin_amdgcn_global_load_lds(
        (__attribute__((address_space(1))) void*)(u16*)g,
        (__attribute__((address_space(3))) void*)l, 16, 0, 0);
}

// ---------------- fp32 -> bf16 convert, 4 elems/thread ----------------
__global__ __launch_bounds__(256) void convert_k(const float* __restrict__ in, u16* __restrict__ out,
                                                 long n) {
    long i = ((long)blockIdx.x * 256 + threadIdx.x) * 4;
    if (i >= n) return;
    float4 v = *(const float4*)(in + i);
    ushort4 o;
    o.x = f2bf(v.x); o.y = f2bf(v.y); o.z = f2bf(v.z); o.w = f2bf(v.w);
    *(ushort4*)(out + i) = o;
}

__global__ __launch_bounds__(128) void convert_small_k(const float* __restrict__ qw,
                                                       const float* __restrict__ kw,
                                                       u16* qwb, u16* kwb) {
    int t = threadIdx.x;
    qwb[t] = f2bf(qw[t]);
    kwb[t] = f2bf(kw[t]);
}

// ---------------- fp32 transpose + convert: in (R,C) fp32 -> out (C,R) bf16 ----------------
__global__ __launch_bounds__(256) void transpose_f32_k(const float* __restrict__ in,
                                                       u16* __restrict__ out, int R, int C) {
    __shared__ u16 tile[64][65];
    const int tid = threadIdx.x;
    const long r0 = (long)blockIdx.y * 64, c0 = (long)blockIdx.x * 64;
    for (int j = 0; j < 4; j++) {
        int c = j * 256 + tid;
        int lr = c >> 4, lc = (c & 15) * 4;
        float4 v = *(const float4*)&in[(r0 + lr) * (long)C + c0 + lc];
        tile[lr][lc + 0] = f2bf(v.x); tile[lr][lc + 1] = f2bf(v.y);
        tile[lr][lc + 2] = f2bf(v.z); tile[lr][lc + 3] = f2bf(v.w);
    }
    __syncthreads();
    for (int j = 0; j < 4; j++) {
        int c = j * 256 + tid;
        int orow = c >> 4, oc = (c & 15) * 4;
        ushort4 vv;
        vv.x = tile[oc + 0][orow]; vv.y = tile[oc + 1][orow];
        vv.z = tile[oc + 2][orow]; vv.w = tile[oc + 3][orow];
        *(ushort4*)&out[(c0 + orow) * (long)R + r0 + oc] = vv;
    }
}

// ---------------- bf16 transpose w/ input row stride: in (R,C)@inRS -> out (C,R) ----------------
__global__ __launch_bounds__(256) void transpose_bf_k(const u16* __restrict__ in, long inRS,
                                                      u16* __restrict__ out, int R, int C) {
    __shared__ u16 tile[64][65];
    const int tid = threadIdx.x;
    const long r0 = (long)blockIdx.y * 64, c0 = (long)blockIdx.x * 64;
    for (int j = 0; j < 4; j++) {
        int c = j * 256 + tid;
        int lr = c >> 4, lc = (c & 15) * 4;
        ushort4 vv = *(const ushort4*)&in[(r0 + lr) * inRS + c0 + lc];
        tile[lr][lc + 0] = vv.x; tile[lr][lc + 1] = vv.y;
        tile[lr][lc + 2] = vv.z; tile[lr][lc + 3] = vv.w;
    }
    __syncthreads();
    for (int j = 0; j < 4; j++) {
        int c = j * 256 + tid;
        int orow = c >> 4, oc = (c & 15) * 4;
        ushort4 vv;
        vv.x = tile[oc + 0][orow]; vv.y = tile[oc + 1][orow];
        vv.z = tile[oc + 2][orow]; vv.w = tile[oc + 3][orow];
        *(ushort4*)&out[(c0 + orow) * (long)R + r0 + oc] = vv;
    }
}

// ---------------- GEMM: C(M,N) = A(M,K) * Bt(N,K)^T, bf16 in, OutT out ----------------
template <typename OutT>
__global__ __launch_bounds__(256) void gemm_bt(const u16* __restrict__ A, const u16* __restrict__ Bt,
                                               OutT* __restrict__ C, int M, int N, int K) {
    __shared__ u16 As[128 * 32];
    __shared__ u16 Bs[128 * 32];
    const int tid = threadIdx.x;
    const int lane = tid & 63, wave = tid >> 6;
    const int l15 = lane & 15, quad = lane >> 4;
    const long m0 = (long)blockIdx.y * 128, n0 = (long)blockIdx.x * 128;
    const int wm = (wave >> 1) * 64, wn = (wave & 1) * 64;

    f32x4 acc[4][4];
    for (int i = 0; i < 4; i++)
        for (int j = 0; j < 4; j++) acc[i][j] = {0.f, 0.f, 0.f, 0.f};

    const u16* aG = A + (m0 + wave * 32 + (lane >> 2)) * (long)K + (lane & 3) * 8;
    const u16* bG = Bt + (n0 + wave * 32 + (lane >> 2)) * (long)K + (lane & 3) * 8;
    u16* aL = &As[wave * 1024];
    u16* bL = &Bs[wave * 1024];
    const long rowK16 = 16L * K;

    for (int kt = 0; kt < K; kt += 32) {
        cp16(aG + kt, aL);
        cp16(aG + kt + rowK16, aL + 512);
        cp16(bG + kt, bL);
        cp16(bG + kt + rowK16, bL + 512);
        __syncthreads();
        bf16x8 af[4], bfr[4];
        for (int mi = 0; mi < 4; mi++)
            af[mi] = *(const bf16x8*)&As[(wm + mi * 16 + l15) * 32 + quad * 8];
        for (int ni = 0; ni < 4; ni++)
            bfr[ni] = *(const bf16x8*)&Bs[(wn + ni * 16 + l15) * 32 + quad * 8];
        for (int mi = 0; mi < 4; mi++)
            for (int ni = 0; ni < 4; ni++)
                acc[mi][ni] = mfma16(af[mi], bfr[ni], acc[mi][ni]);
        __syncthreads();
    }
    for (int mi = 0; mi < 4; mi++)
        for (int r = 0; r < 4; r++) {
            long row = m0 + wm + mi * 16 + quad * 4 + r;
            OutT* crow = C + row * (long)N + n0 + wn + l15;
            for (int ni = 0; ni < 4; ni++) {
                float v = acc[mi][ni][r];
                if constexpr (sizeof(OutT) == 2) crow[ni * 16] = f2bf(v);
                else crow[ni * 16] = v;
            }
        }
}

// ---------------- RMSNorm + RoPE + scale (fp32 cos/sin), one wave per 128-elem row ----------------
__global__ __launch_bounds__(256) void normrope(u16* __restrict__ buf, long rowstride, int heads,
                                                const u16* __restrict__ w,
                                                const float* __restrict__ cosf, const float* __restrict__ sinf,
                                                float scale) {
    const int row = blockIdx.x * 4 + (threadIdx.x >> 6);
    const int lane = threadIdx.x & 63;
    u16* p = buf + (long)(row / heads) * rowstride + (row % heads) * 128;
    float x1 = bf2f(p[lane]);
    float x2 = bf2f(p[lane + 64]);
    float ss = x1 * x1 + x2 * x2;
    for (int off = 1; off < 64; off <<= 1) ss += __shfl_xor(ss, off);
    float inv = rsqrtf(ss * (1.f / 128.f) + 1e-6f);
    int s = (row / heads) % SLEN;
    float c1 = cosf[s * 128 + lane], c2 = cosf[s * 128 + 64 + lane];
    float s1 = sinf[s * 128 + lane], s2 = sinf[s * 128 + 64 + lane];
    float w1 = bf2f(w[lane]), w2 = bf2f(w[lane + 64]);
    float y1 = x1 * inv * w1, y2 = x2 * inv * w2;
    p[lane]      = f2bf((y1 * c1 - y2 * s1) * scale);
    p[lane + 64] = f2bf((y2 * c2 + y1 * s2) * scale);
}

// ---------------- causal flash attention v3: barrier-free, direct-from-L2 fragments ----------------
// qkv: (B*S, 3072) fused [q | k | v], q/k normed+roped (q scaled); vT: (512, B*S)
// ctx out: (B*S, 2048). Block = 4 waves x 32 q-rows = 128 rows of one (b,h).
// blockIdx%8 == (b,g) so each XCD's L2 holds exactly one K/vT working set (1 MB).
// S^T = K*Q^T via operand swap; row-stats in-lane; rowsum via ones-MFMA.
__global__ __launch_bounds__(256, 2) void attn(const u16* __restrict__ qkv, const u16* __restrict__ vT,
                                               u16* __restrict__ ctx) {
    __shared__ u16 Ps[4][2][16][72];   // [wave][m][qrow16][t+pad]
    __shared__ float Al[4][2][16];     // alpha axis-swap
    const int tid = threadIdx.x;
    const int lane = tid & 63, wave = tid >> 6;
    const int l15 = lane & 15, quad = lane >> 4;
    const int bg = blockIdx.x & 7, b = bg >> 2, g = bg & 3;
    const int rest = blockIdx.x >> 3;
    const int h = g * 4 + (rest & 3);
    const int qt = 15 - (rest >> 2);        // longest first within each XCD
    const int wr = qt * 128 + wave * 32;    // this wave's first q-row

    union { bf16x8 v; u16 s[8]; } uo;
    for (int j = 0; j < 8; j++) uo.s[j] = 0x3F80;  // bf16 1.0
    const bf16x8 ones = uo.v;

    // Q fragments (B-operand layout; identical register layout to A)
    bf16x8 qa[2][4];
    for (int m = 0; m < 2; m++) {
        const u16* qp = qkv + (long)(b * SLEN + wr + m * 16 + l15) * 3072 + h * 128 + quad * 8;
        for (int kc = 0; kc < 4; kc++) qa[m][kc] = *(const bf16x8*)(qp + kc * 32);
    }
    float m_i[2] = {-__builtin_inff(), -__builtin_inff()};  // per q-row (m*16+l15)
    f32x4 l_acc[2];
    f32x4 o[2][8];
    for (int m = 0; m < 2; m++) l_acc[m] = {0.f, 0.f, 0.f, 0.f};
    for (int m = 0; m < 2; m++)
        for (int nf = 0; nf < 8; nf++) o[m][nf] = {0.f, 0.f, 0.f, 0.f};

    const u16* kbase = qkv + (long)b * SLEN * 3072 + 2048 + g * 128;
    const u16* vbase = vT + (long)g * 128 * 4096 + (long)b * SLEN;

    for (int t0 = 0; t0 <= wr + 31; t0 += 64) {
        // K fragments (A-operand: lane row = t)
        bf16x8 kf[4][4];
        #pragma unroll
        for (int nf = 0; nf < 4; nf++) {
            const u16* kp = kbase + (long)(t0 + nf * 16 + l15) * 3072 + quad * 8;
            #pragma unroll
            for (int kc = 0; kc < 4; kc++) kf[nf][kc] = *(const bf16x8*)(kp + kc * 32);
        }
        // V first half early (latency hidden under QK + softmax)
        bf16x8 vf0[8];
        #pragma unroll
        for (int nf = 0; nf < 8; nf++)
            vf0[nf] = *(const bf16x8*)(vbase + (long)(nf * 16 + l15) * 4096 + t0 + quad * 8);

        // S^T = K * Q^T
        f32x4 sc[2][4];
        for (int m = 0; m < 2; m++)
            for (int nf = 0; nf < 4; nf++) sc[m][nf] = {0.f, 0.f, 0.f, 0.f};
        #pragma unroll
        for (int kc = 0; kc < 4; kc++)
            #pragma unroll
            for (int nf = 0; nf < 4; nf++) {
                sc[0][nf] = mfma16(kf[nf][kc], qa[0][kc], sc[0][nf]);
                sc[1][nf] = mfma16(kf[nf][kc], qa[1][kc], sc[1][nf]);
            }
        // causal mask: t = t0+nf*16+quad*4+r (rows), qrow = wr+m*16+l15 (cols)
        if (t0 + 63 > wr) {
            #pragma unroll
            for (int m = 0; m < 2; m++) {
                int qrow = wr + m * 16 + l15;
                #pragma unroll
                for (int nf = 0; nf < 4; nf++)
                    #pragma unroll
                    for (int r = 0; r < 4; r++)
                        if (t0 + nf * 16 + quad * 4 + r > qrow) sc[m][nf][r] = -__builtin_inff();
            }
        }
        // row max: in-lane over nf,r then across quads (2 shuffles)
        float alpha[2];
        #pragma unroll
        for (int m = 0; m < 2; m++) {
            float mx = sc[m][0][0];
            #pragma unroll
            for (int nf = 0; nf < 4; nf++)
                #pragma unroll
                for (int r = 0; r < 4; r++) mx = fmaxf(mx, sc[m][nf][r]);
            mx = fmaxf(mx, __shfl_xor(mx, 16));
            mx = fmaxf(mx, __shfl_xor(mx, 32));
            float mn = fmaxf(m_i[m], mx);
            alpha[m] = __expf(m_i[m] - mn);
            m_i[m] = mn;
            Al[wave][m][l15] = alpha[m];
        }
        // exp + P store (P^T C-layout -> A-layout rows: 4 consecutive t per lane = b64)
        #pragma unroll
        for (int m = 0; m < 2; m++)
            #pragma unroll
            for (int nf = 0; nf < 4; nf++) {
                ushort4 pk;
                pk.x = f2bf(__expf(sc[m][nf][0] - m_i[m]));
                pk.y = f2bf(__expf(sc[m][nf][1] - m_i[m]));
                pk.z = f2bf(__expf(sc[m][nf][2] - m_i[m]));
                pk.w = f2bf(__expf(sc[m][nf][3] - m_i[m]));
                *(ushort4*)&Ps[wave][m][l15][nf * 16 + quad * 4] = pk;
            }
        memfence_compiler();
        // alpha on O-row axis (broadcast read), rescale o and l
        f32x4 al[2];
        al[0] = *(const f32x4*)&Al[wave][0][quad * 4];
        al[1] = *(const f32x4*)&Al[wave][1][quad * 4];
        #pragma unroll
        for (int m = 0; m < 2; m++) {
            #pragma unroll
            for (int nf = 0; nf < 8; nf++)
                #pragma unroll
                for (int r = 0; r < 4; r++) o[m][nf][r] *= al[m][r];
            #pragma unroll
            for (int r = 0; r < 4; r++) l_acc[m][r] *= al[m][r];
        }
        // PV, half 0 (issue half-1 V loads first so their latency overlaps)
        bf16x8 vf1[8];
        #pragma unroll
        for (int nf = 0; nf < 8; nf++)
            vf1[nf] = *(const bf16x8*)(vbase + (long)(nf * 16 + l15) * 4096 + t0 + 32 + quad * 8);
        {
            bf16x8 pa0 = *(const bf16x8*)&Ps[wave][0][l15][quad * 8];
            bf16x8 pa1 = *(const bf16x8*)&Ps[wave][1][l15][quad * 8];
            #pragma unroll
            for (int nf = 0; nf < 8; nf++) {
                o[0][nf] = mfma16(pa0, vf0[nf], o[0][nf]);
                o[1][nf] = mfma16(pa1, vf0[nf], o[1][nf]);
            }
            l_acc[0] = mfma16(pa0, ones, l_acc[0]);
            l_acc[1] = mfma16(pa1, ones, l_acc[1]);
        }
        // PV, half 1
        {
            bf16x8 pa0 = *(const bf16x8*)&Ps[wave][0][l15][32 + quad * 8];
            bf16x8 pa1 = *(const bf16x8*)&Ps[wave][1][l15][32 + quad * 8];
            #pragma unroll
            for (int nf = 0; nf < 8; nf++) {
                o[0][nf] = mfma16(pa0, vf1[nf], o[0][nf]);
                o[1][nf] = mfma16(pa1, vf1[nf], o[1][nf]);
            }
            l_acc[0] = mfma16(pa0, ones, l_acc[0]);
            l_acc[1] = mfma16(pa1, ones, l_acc[1]);
        }
        memfence_compiler();
    }
    #pragma unroll
    for (int m = 0; m < 2; m++)
        #pragma unroll
        for (int r = 0; r < 4; r++) {
            float inv = 1.f / l_acc[m][r];
            int srow = wr + m * 16 + quad * 4 + r;
            u16* cp = ctx + (long)(b * SLEN + srow) * 2048 + h * 128 + l15;
            #pragma unroll
            for (int nf = 0; nf < 8; nf++) cp[nf * 16] = f2bf(o[m][nf][r] * inv);
        }
}

extern "C" void kernel_launch(void* const* d_in, const int* in_sizes, int n_in,
                              void* d_out, int out_size, void* d_ws, size_t ws_size,
                              hipStream_t stream) {
    const float* x    = (const float*)d_in[0];
    // d_in[1] = mask (unused; causality from indices)
    const float* cosi = (const float*)d_in[2];
    const float* sini = (const float*)d_in[3];
    const float* Wq   = (const float*)d_in[4];
    const float* Wk   = (const float*)d_in[5];
    const float* Wv   = (const float*)d_in[6];
    const float* Wo   = (const float*)d_in[7];
    const float* qw   = (const float*)d_in[8];
    const float* kw   = (const float*)d_in[9];
    float* out = (float*)d_out;
    char* ws = (char*)d_ws;

    const size_t MB = 1 << 20;
    u16* qkvb  = (u16*)(ws);             // 4096x3072 bf16 = 24 MB  [0,24)
    u16* vTb   = (u16*)(ws + 24 * MB);   // 512x4096        = 4 MB  [24,28)
    u16* xbf   = (u16*)(ws + 28 * MB);   // 4096x2048       = 16 MB [28,44) dead after QKV GEMM
    u16* ctx   = (u16*)(ws + 28 * MB);   // reuses xbf region
    u16* wqkvT = (u16*)(ws + 44 * MB);   // 3072x2048       = 12 MB [44,56) dead after QKV GEMM
    u16* woT   = (u16*)(ws + 44 * MB);   // reuses wqkvT region (8 MB)
    u16* qwb   = (u16*)(ws + 56 * MB);
    u16* kwb   = (u16*)(ws + 56 * MB + 256);

    convert_k<<<8192, 256, 0, stream>>>(x, xbf, 8388608L);
    convert_small_k<<<1, 128, 0, stream>>>(qw, kw, qwb, kwb);

    // fused weight: rows 0..2047 = Wq^T, 2048..2559 = Wk^T, 2560..3071 = Wv^T
    transpose_f32_k<<<dim3(32, 32), 256, 0, stream>>>(Wq, wqkvT, 2048, 2048);
    transpose_f32_k<<<dim3(8, 32), 256, 0, stream>>>(Wk, wqkvT + 2048L * 2048, 2048, 512);
    transpose_f32_k<<<dim3(8, 32), 256, 0, stream>>>(Wv, wqkvT + 2560L * 2048, 2048, 512);

    gemm_bt<u16><<<dim3(24, 32), 256, 0, stream>>>(xbf, wqkvT, qkvb, 4096, 3072, 2048);

    // v columns (2560..3071) -> vT (512, 4096)
    transpose_bf_k<<<dim3(8, 64), 256, 0, stream>>>(qkvb + 2560, 3072L, vTb, 4096, 512);

    normrope<<<16384, 256, 0, stream>>>(qkvb, 3072L, NHEADS, qwb, cosi, sini, 0.08838834764831845f);
    normrope<<<4096, 256, 0, stream>>>(qkvb + 2048, 3072L, NGRP, kwb, cosi, sini, 1.0f);

    // Wo^T into the (now dead) wqkvT region
    transpose_f32_k<<<dim3(32, 32), 256, 0, stream>>>(Wo, woT, 2048, 2048);

    attn<<<dim3(512, 1, 1), 256, 0, stream>>>(qkvb, vTb, ctx);

    gemm_bt<float><<<dim3(16, 32), 256, 0, stream>>>(ctx, woT, out, 4096, 2048, 2048);
}